// Round 1
// baseline (212.942 us; speedup 1.0000x reference)
//
#include <hip/hip_runtime.h>

#define S 7
#define NUM_CLASSES 20
#define BATCH 16384
#define NCELLS (BATCH * S * S)   // 802816
#define BLOCK 256

__device__ __forceinline__ float iou_f(float acx, float acy, float aw, float ah,
                                       float bcx, float bcy, float bw, float bh) {
    float ax1 = acx - aw * 0.5f, ay1 = acy - ah * 0.5f;
    float ax2 = acx + aw * 0.5f, ay2 = acy + ah * 0.5f;
    float bx1 = bcx - bw * 0.5f, by1 = bcy - bh * 0.5f;
    float bx2 = bcx + bw * 0.5f, by2 = bcy + bh * 0.5f;
    float iw = fminf(ax2, bx2) - fmaxf(ax1, bx1);
    iw = fmaxf(iw, 0.0f);
    float ih = fminf(ay2, by2) - fmaxf(ay1, by1);
    ih = fmaxf(ih, 0.0f);
    float inter = iw * ih;
    float uni = aw * ah + bw * bh - inter;
    return inter / (uni + 1e-10f);
}

__global__ void zero_out_kernel(float* out) {
    out[0] = 0.0f;
}

__global__ __launch_bounds__(BLOCK) void yolo_loss_kernel(
        const float* __restrict__ preds,
        const float* __restrict__ labels,
        float* __restrict__ out) {
    int cell = blockIdx.x * BLOCK + threadIdx.x;   // grid exactly covers NCELLS

    float p[30], l[30];
    const float2* pp = (const float2*)(preds + (size_t)cell * 30);
    const float2* ll = (const float2*)(labels + (size_t)cell * 30);
#pragma unroll
    for (int j = 0; j < 15; ++j) {
        float2 v = pp[j];
        p[2 * j] = v.x; p[2 * j + 1] = v.y;
        float2 w = ll[j];
        l[2 * j] = w.x; l[2 * j + 1] = w.y;
    }

    float obj = (l[4] == 1.0f) ? 1.0f : 0.0f;

    float iou1 = iou_f(p[0], p[1], p[2], p[3], l[0], l[1], l[2], l[3]);
    float iou2 = iou_f(p[5], p[6], p[7], p[8], l[0], l[1], l[2], l[3]);
    bool b1 = iou1 > iou2;

    // responsible box slices (labels[5:9] is bitwise-identical to labels[0:4]
    // by construction: labels = concat([box, conf, box, conf, cls]))
    float pxy0 = b1 ? p[0] : p[5];
    float pxy1 = b1 ? p[1] : p[6];
    float pwh0 = b1 ? p[2] : p[7];
    float pwh1 = b1 ? p[3] : p[8];
    float conf_resp  = b1 ? p[4] : p[9];
    float conf_other = b1 ? p[9] : p[4];
    float iou_resp   = b1 ? iou1 : iou2;
    float iou_other  = b1 ? iou2 : iou1;

    float dx = pxy0 - l[0];
    float dy = pxy1 - l[1];
    float loss_xy = dx * dx + dy * dy;

    float sw0 = sqrtf(pwh0) - sqrtf(l[2]);
    float sw1 = sqrtf(pwh1) - sqrtf(l[3]);
    float loss_wh = sw0 * sw0 + sw1 * sw1;

    float d_obj = conf_resp - iou_resp;
    float loss_obj = d_obj * d_obj;

    float d_no = conf_other - iou_other;
    float loss_noobj_in = 0.5f * d_no * d_no;

    float loss_noobj_out = 0.5f * (1.0f - obj) * (p[4] * p[4] + p[9] * p[9]);

    float loss_cls = 0.0f;
#pragma unroll
    for (int c = 10; c < 30; ++c) {
        float d = p[c] - l[c];
        loss_cls += d * d;
    }

    float loss = obj * (5.0f * loss_xy + loss_wh + loss_obj + loss_noobj_in + loss_cls)
               + loss_noobj_out;

    // wave-64 reduction
#pragma unroll
    for (int off = 32; off > 0; off >>= 1)
        loss += __shfl_down(loss, off, 64);

    __shared__ float wsum[BLOCK / 64];
    int lane = threadIdx.x & 63;
    int wid  = threadIdx.x >> 6;
    if (lane == 0) wsum[wid] = loss;
    __syncthreads();
    if (threadIdx.x == 0) {
        float s = wsum[0] + wsum[1] + wsum[2] + wsum[3];
        atomicAdd(out, s * (1.0f / (float)BATCH));
    }
}

extern "C" void kernel_launch(void* const* d_in, const int* in_sizes, int n_in,
                              void* d_out, int out_size, void* d_ws, size_t ws_size,
                              hipStream_t stream) {
    const float* preds  = (const float*)d_in[0];
    const float* labels = (const float*)d_in[1];
    float* out = (float*)d_out;

    zero_out_kernel<<<1, 1, 0, stream>>>(out);

    int nblocks = NCELLS / BLOCK;   // 3136, exact
    yolo_loss_kernel<<<nblocks, BLOCK, 0, stream>>>(preds, labels, out);
}

// Round 2
// 209.353 us; speedup vs baseline: 1.0171x; 1.0171x over previous
//
#include <hip/hip_runtime.h>

#define S 7
#define NUM_CLASSES 20
#define BATCH 16384
#define NCELLS (BATCH * S * S)   // 802816
#define BLOCK 256
#define CPB   256                 // cells per block (== BLOCK)
#define TILE_FLOATS (CPB * 30)    // 7680 floats per array per block
#define TILE_F4     (TILE_FLOATS / 4)  // 1920

__device__ __forceinline__ float iou_f(float acx, float acy, float aw, float ah,
                                       float bcx, float bcy, float bw, float bh) {
    float ax1 = acx - aw * 0.5f, ay1 = acy - ah * 0.5f;
    float ax2 = acx + aw * 0.5f, ay2 = acy + ah * 0.5f;
    float bx1 = bcx - bw * 0.5f, by1 = bcy - bh * 0.5f;
    float bx2 = bcx + bw * 0.5f, by2 = bcy + bh * 0.5f;
    float iw = fminf(ax2, bx2) - fmaxf(ax1, bx1);
    iw = fmaxf(iw, 0.0f);
    float ih = fminf(ay2, by2) - fmaxf(ay1, by1);
    ih = fmaxf(ih, 0.0f);
    float inter = iw * ih;
    float uni = aw * ah + bw * bh - inter;
    return inter / (uni + 1e-10f);
}

__global__ void zero_out_kernel(float* out) {
    out[0] = 0.0f;
}

__global__ __launch_bounds__(BLOCK) void yolo_loss_kernel(
        const float* __restrict__ preds,
        const float* __restrict__ labels,
        float* __restrict__ out) {
    // ---- stage the block's tile into LDS with coalesced float4 loads ----
    __shared__ float sp[TILE_FLOATS];   // 30720 B
    __shared__ float sl[TILE_FLOATS];   // 30720 B

    const float4* gp = (const float4*)(preds  + (size_t)blockIdx.x * TILE_FLOATS);
    const float4* gl = (const float4*)(labels + (size_t)blockIdx.x * TILE_FLOATS);
    float4* sp4 = (float4*)sp;
    float4* sl4 = (float4*)sl;

#pragma unroll
    for (int it = 0; it < 8; ++it) {
        int i = threadIdx.x + it * BLOCK;
        if (i < TILE_F4) {
            sp4[i] = gp[i];
            sl4[i] = gl[i];
        }
    }
    __syncthreads();

    // ---- per-cell loss from LDS ----
    float p[30], l[30];
    const float2* pp = (const float2*)(sp + threadIdx.x * 30);
    const float2* ll = (const float2*)(sl + threadIdx.x * 30);
#pragma unroll
    for (int j = 0; j < 15; ++j) {
        float2 v = pp[j];
        p[2 * j] = v.x; p[2 * j + 1] = v.y;
        float2 w = ll[j];
        l[2 * j] = w.x; l[2 * j + 1] = w.y;
    }

    float obj = (l[4] == 1.0f) ? 1.0f : 0.0f;

    float iou1 = iou_f(p[0], p[1], p[2], p[3], l[0], l[1], l[2], l[3]);
    float iou2 = iou_f(p[5], p[6], p[7], p[8], l[0], l[1], l[2], l[3]);
    bool b1 = iou1 > iou2;

    // labels[5:9] is bitwise-identical to labels[0:4] by construction
    float pxy0 = b1 ? p[0] : p[5];
    float pxy1 = b1 ? p[1] : p[6];
    float pwh0 = b1 ? p[2] : p[7];
    float pwh1 = b1 ? p[3] : p[8];
    float conf_resp  = b1 ? p[4] : p[9];
    float conf_other = b1 ? p[9] : p[4];
    float iou_resp   = b1 ? iou1 : iou2;
    float iou_other  = b1 ? iou2 : iou1;

    float dx = pxy0 - l[0];
    float dy = pxy1 - l[1];
    float loss_xy = dx * dx + dy * dy;

    float sw0 = sqrtf(pwh0) - sqrtf(l[2]);
    float sw1 = sqrtf(pwh1) - sqrtf(l[3]);
    float loss_wh = sw0 * sw0 + sw1 * sw1;

    float d_obj = conf_resp - iou_resp;
    float loss_obj = d_obj * d_obj;

    float d_no = conf_other - iou_other;
    float loss_noobj_in = 0.5f * d_no * d_no;

    float loss_noobj_out = 0.5f * (1.0f - obj) * (p[4] * p[4] + p[9] * p[9]);

    float loss_cls = 0.0f;
#pragma unroll
    for (int c = 10; c < 30; ++c) {
        float d = p[c] - l[c];
        loss_cls += d * d;
    }

    float loss = obj * (5.0f * loss_xy + loss_wh + loss_obj + loss_noobj_in + loss_cls)
               + loss_noobj_out;

    // ---- wave-64 shuffle reduction, then cross-wave via LDS ----
#pragma unroll
    for (int off = 32; off > 0; off >>= 1)
        loss += __shfl_down(loss, off, 64);

    __shared__ float wsum[BLOCK / 64];
    int lane = threadIdx.x & 63;
    int wid  = threadIdx.x >> 6;
    if (lane == 0) wsum[wid] = loss;
    __syncthreads();
    if (threadIdx.x == 0) {
        float s = wsum[0] + wsum[1] + wsum[2] + wsum[3];
        atomicAdd(out, s * (1.0f / (float)BATCH));
    }
}

extern "C" void kernel_launch(void* const* d_in, const int* in_sizes, int n_in,
                              void* d_out, int out_size, void* d_ws, size_t ws_size,
                              hipStream_t stream) {
    const float* preds  = (const float*)d_in[0];
    const float* labels = (const float*)d_in[1];
    float* out = (float*)d_out;

    zero_out_kernel<<<1, 1, 0, stream>>>(out);

    int nblocks = NCELLS / CPB;   // 3136, exact
    yolo_loss_kernel<<<nblocks, BLOCK, 0, stream>>>(preds, labels, out);
}

// Round 3
// 205.177 us; speedup vs baseline: 1.0378x; 1.0204x over previous
//
#include <hip/hip_runtime.h>

#define S 7
#define NUM_CLASSES 20
#define BATCH 16384
#define NCELLS (BATCH * S * S)   // 802816
#define BLOCK 256
#define CPB   256                 // cells per block
#define TILE_FLOATS (CPB * 30)    // 7680 floats per array per block
#define TILE_F4     (TILE_FLOATS / 4)  // 1920

__device__ __forceinline__ void async_load16(const float* g, float* s) {
    // async global -> LDS DMA, 16 B per lane; LDS dst is wave-uniform base +
    // lane*16, which our mapping satisfies (consecutive i per lane).
    __builtin_amdgcn_global_load_lds(
        (const __attribute__((address_space(1))) void*)g,
        (__attribute__((address_space(3))) void*)s,
        16, 0, 0);
}

__device__ __forceinline__ float iou_f(float acx, float acy, float aw, float ah,
                                       float bcx, float bcy, float bw, float bh) {
    float ax1 = acx - aw * 0.5f, ay1 = acy - ah * 0.5f;
    float ax2 = acx + aw * 0.5f, ay2 = acy + ah * 0.5f;
    float bx1 = bcx - bw * 0.5f, by1 = bcy - bh * 0.5f;
    float bx2 = bcx + bw * 0.5f, by2 = bcy + bh * 0.5f;
    float iw = fminf(ax2, bx2) - fmaxf(ax1, bx1);
    iw = fmaxf(iw, 0.0f);
    float ih = fminf(ay2, by2) - fmaxf(ay1, by1);
    ih = fmaxf(ih, 0.0f);
    float inter = iw * ih;
    float uni = aw * ah + bw * bh - inter;
    return inter / (uni + 1e-10f);
}

__global__ __launch_bounds__(BLOCK) void yolo_loss_kernel(
        const float* __restrict__ preds,
        const float* __restrict__ labels,
        float* __restrict__ out) {
    __shared__ float sp[TILE_FLOATS];   // 30720 B
    __shared__ float sl[TILE_FLOATS];   // 30720 B

    const float* gp = preds  + (size_t)blockIdx.x * TILE_FLOATS;
    const float* gl = labels + (size_t)blockIdx.x * TILE_FLOATS;

    // ---- async staging: all loads in flight, single drain at the barrier ----
#pragma unroll
    for (int it = 0; it < 8; ++it) {
        int i = (threadIdx.x + it * BLOCK) * 4;   // float index, 16 B granules
        if (i < TILE_FLOATS) {
            async_load16(gp + i, sp + i);
            async_load16(gl + i, sl + i);
        }
    }
    __syncthreads();   // emits s_waitcnt vmcnt(0) + s_barrier

    // ---- per-cell loss from LDS ----
    float p[30], l[30];
    const float2* pp = (const float2*)(sp + threadIdx.x * 30);
    const float2* ll = (const float2*)(sl + threadIdx.x * 30);
#pragma unroll
    for (int j = 0; j < 15; ++j) {
        float2 v = pp[j];
        p[2 * j] = v.x; p[2 * j + 1] = v.y;
        float2 w = ll[j];
        l[2 * j] = w.x; l[2 * j + 1] = w.y;
    }

    float obj = (l[4] == 1.0f) ? 1.0f : 0.0f;

    float iou1 = iou_f(p[0], p[1], p[2], p[3], l[0], l[1], l[2], l[3]);
    float iou2 = iou_f(p[5], p[6], p[7], p[8], l[0], l[1], l[2], l[3]);
    bool b1 = iou1 > iou2;

    // labels[5:9] is bitwise-identical to labels[0:4] by construction
    float pxy0 = b1 ? p[0] : p[5];
    float pxy1 = b1 ? p[1] : p[6];
    float pwh0 = b1 ? p[2] : p[7];
    float pwh1 = b1 ? p[3] : p[8];
    float conf_resp  = b1 ? p[4] : p[9];
    float conf_other = b1 ? p[9] : p[4];
    float iou_resp   = b1 ? iou1 : iou2;
    float iou_other  = b1 ? iou2 : iou1;

    float dx = pxy0 - l[0];
    float dy = pxy1 - l[1];
    float loss_xy = dx * dx + dy * dy;

    float sw0 = sqrtf(pwh0) - sqrtf(l[2]);
    float sw1 = sqrtf(pwh1) - sqrtf(l[3]);
    float loss_wh = sw0 * sw0 + sw1 * sw1;

    float d_obj = conf_resp - iou_resp;
    float loss_obj = d_obj * d_obj;

    float d_no = conf_other - iou_other;
    float loss_noobj_in = 0.5f * d_no * d_no;

    float loss_noobj_out = 0.5f * (1.0f - obj) * (p[4] * p[4] + p[9] * p[9]);

    float loss_cls = 0.0f;
#pragma unroll
    for (int c = 10; c < 30; ++c) {
        float d = p[c] - l[c];
        loss_cls += d * d;
    }

    float loss = obj * (5.0f * loss_xy + loss_wh + loss_obj + loss_noobj_in + loss_cls)
               + loss_noobj_out;

    // ---- wave-64 shuffle reduction, then cross-wave via LDS ----
#pragma unroll
    for (int off = 32; off > 0; off >>= 1)
        loss += __shfl_down(loss, off, 64);

    __shared__ float wsum[BLOCK / 64];
    int lane = threadIdx.x & 63;
    int wid  = threadIdx.x >> 6;
    if (lane == 0) wsum[wid] = loss;
    __syncthreads();
    if (threadIdx.x == 0) {
        float s = wsum[0] + wsum[1] + wsum[2] + wsum[3];
        atomicAdd(out, s * (1.0f / (float)BATCH));
    }
}

extern "C" void kernel_launch(void* const* d_in, const int* in_sizes, int n_in,
                              void* d_out, int out_size, void* d_ws, size_t ws_size,
                              hipStream_t stream) {
    const float* preds  = (const float*)d_in[0];
    const float* labels = (const float*)d_in[1];
    float* out = (float*)d_out;

    hipMemsetAsync(out, 0, sizeof(float), stream);  // capture-legal memset node

    int nblocks = NCELLS / CPB;   // 3136, exact
    yolo_loss_kernel<<<nblocks, BLOCK, 0, stream>>>(preds, labels, out);
}